// Round 11
// baseline (541.665 us; speedup 1.0000x reference)
//
#include <hip/hip_runtime.h>
#include <hip/hip_cooperative_groups.h>

namespace cg = cooperative_groups;

// N = 50000 nodes, E = 400000 edges/network, M = 3 networks,
// H = 4 heads, D = 64 -> CH = 256 channels, fp32 in/out.
#define N_NODES 50000
#define N_EDGES 400000
#define TOT_E   (3 * N_EDGES)
#define CH      256
#define NHEADS  4
#define BUCKET  64       // per-node bucket stride (mean degree 24, P(>64)~2e-14)
#define GEMM_TILES ((N_NODES + 63) / 64)   // 782

typedef __attribute__((ext_vector_type(8))) short short8v;
typedef __attribute__((ext_vector_type(8))) unsigned short ushort8v;
typedef __attribute__((ext_vector_type(4))) float float4v;

__device__ inline unsigned short f2b(float f) {  // fp32 -> bf16 RTNE
  union { float f; unsigned u; } x; x.f = f;
  return (unsigned short)((x.u + 0x7FFFu + ((x.u >> 16) & 1u)) >> 16);
}
__device__ inline float b2f(unsigned short s) {
  union { unsigned u; float f; } x; x.u = ((unsigned)s) << 16;
  return x.f;
}

__device__ inline float alpha_of(int gid, int h, const float* __restrict__ a0,
                                 const float* __restrict__ a1,
                                 const float* __restrict__ a2,
                                 float w0, float w1, float w2) {
  int net = (gid >= 2 * N_EDGES) ? 2 : (gid >= N_EDGES ? 1 : 0);
  int e = gid - net * N_EDGES;
  const float* at = (net == 0) ? a0 : (net == 1 ? a1 : a2);
  float w = (net == 0) ? w0 : (net == 1 ? w1 : w2);
  return w * at[(size_t)e * NHEADS + h];
}

// ===========================================================================
// Shared phase bodies (used by both the cooperative mega kernel and the
// fallback 4-kernel path). All grid-stride over `nthreads` total threads.
// ===========================================================================
__device__ inline void phase_prep(int gtid, int nthreads,
                                  const float* __restrict__ W,
                                  unsigned short* __restrict__ WTp,
                                  int* __restrict__ cursor) {
  for (int i = gtid; i < N_NODES; i += nthreads) cursor[i] = 0;
  for (int i = gtid; i < 8192; i += nthreads) {
    int f = i >> 9, ks = (i >> 6) & 7, l = i & 63;
    int lr = l & 15, lk = l >> 4;
    unsigned short* dst = WTp + (size_t)i * 8;
    #pragma unroll
    for (int j = 0; j < 8; ++j)
      dst[j] = f2b(W[(ks * 32 + lk * 8 + j) * 256 + f * 16 + lr]);
  }
}

__device__ inline void phase_gemm(int bid, int nblocks, int tid,
                                  const float* __restrict__ x,
                                  const unsigned short* __restrict__ WTp,
                                  unsigned short* __restrict__ xpb) {
  const int w = tid >> 6;
  const int l = tid & 63;
  const int lr = l & 15, lk = l >> 4;
  const short8v* __restrict__ wp = (const short8v*)WTp;

  for (int tile = bid; tile < GEMM_TILES; tile += nblocks) {
    const int xrow = tile * 64 + w * 16 + lr;
    const bool valid = (xrow < N_NODES);

    float4v acc[16];
    #pragma unroll
    for (int f = 0; f < 16; ++f) acc[f] = (float4v)0.0f;

    for (int ks = 0; ks < 8; ++ks) {
      short8v b;
      if (valid) {
        const float4* px = (const float4*)(x + (size_t)xrow * 256 + ks * 32 + lk * 8);
        float4 u0 = px[0], u1 = px[1];
        b[0]=(short)f2b(u0.x); b[1]=(short)f2b(u0.y); b[2]=(short)f2b(u0.z); b[3]=(short)f2b(u0.w);
        b[4]=(short)f2b(u1.x); b[5]=(short)f2b(u1.y); b[6]=(short)f2b(u1.z); b[7]=(short)f2b(u1.w);
      } else {
        b = (short8v)0;
      }
      #pragma unroll
      for (int f = 0; f < 16; ++f) {
        short8v a = wp[(f * 8 + ks) * 64 + l];
        acc[f] = __builtin_amdgcn_mfma_f32_16x16x32_bf16(a, b, acc[f], 0, 0, 0);
      }
    }

    if (valid) {
      unsigned short* rowp = xpb + (size_t)xrow * 256 + lk * 4;
      #pragma unroll
      for (int f = 0; f < 16; ++f) {
        ushort4 pk;
        pk.x = f2b(acc[f][0]);
        pk.y = f2b(acc[f][1]);
        pk.z = f2b(acc[f][2]);
        pk.w = f2b(acc[f][3]);
        *(ushort4*)(rowp + f * 16) = pk;
      }
    }
  }
}

__device__ inline void phase_fill(int gtid, int nthreads,
                                  const int* __restrict__ e0,
                                  const int* __restrict__ e1,
                                  const int* __restrict__ e2,
                                  int* __restrict__ cursor,
                                  long long* __restrict__ recs2) {
  for (int g = gtid; g < TOT_E; g += nthreads) {
    int net = (g >= 2 * N_EDGES) ? 2 : (g >= N_EDGES ? 1 : 0);
    int e = g - net * N_EDGES;
    const int* ei = (net == 0) ? e0 : (net == 1 ? e1 : e2);
    int src = ei[e];
    int dst = ei[N_EDGES + e];
    int pos = atomicAdd(&cursor[dst], 1);
    if (pos < BUCKET)
      recs2[(size_t)dst * BUCKET + pos] = ((long long)g << 32) | (unsigned)src;
  }
}

__device__ inline void phase_gather(int gwave, int nwaves, int lane,
                                    const long long* __restrict__ recs2,
                                    const int* __restrict__ cursor,
                                    const float* __restrict__ a0,
                                    const float* __restrict__ a1,
                                    const float* __restrict__ a2,
                                    const float* __restrict__ nw,
                                    const unsigned short* __restrict__ xpb,
                                    const float* __restrict__ bias,
                                    float* __restrict__ out) {
  const int half = lane >> 5;
  const int l = lane & 31;
  const int c = l * 8;         // channel base (8 bf16 per lane)
  const int h = l >> 3;        // head (8 lanes per head)
  const float w0 = nw[0], w1 = nw[1], w2 = nw[2];

  for (int u = gwave; u < N_NODES / 2; u += nwaves) {
    const int n = u * 2 + half;
    const int cnt = min(cursor[n], BUCKET);
    const int2* __restrict__ rp = (const int2*)(recs2 + (size_t)n * BUCKET);

    float acc[8] = {};
    int i = 0;
    for (; i + 4 <= cnt; i += 4) {
      int2 r0 = rp[i + 0], r1 = rp[i + 1], r2 = rp[i + 2], r3 = rp[i + 3];
      float A0 = alpha_of(r0.y, h, a0, a1, a2, w0, w1, w2);
      float A1 = alpha_of(r1.y, h, a0, a1, a2, w0, w1, w2);
      float A2 = alpha_of(r2.y, h, a0, a1, a2, w0, w1, w2);
      float A3 = alpha_of(r3.y, h, a0, a1, a2, w0, w1, w2);
      ushort8v v0 = *(const ushort8v*)(xpb + (size_t)r0.x * CH + c);
      ushort8v v1 = *(const ushort8v*)(xpb + (size_t)r1.x * CH + c);
      ushort8v v2 = *(const ushort8v*)(xpb + (size_t)r2.x * CH + c);
      ushort8v v3 = *(const ushort8v*)(xpb + (size_t)r3.x * CH + c);
      #pragma unroll
      for (int j = 0; j < 8; ++j) {
        acc[j] += A0 * b2f(v0[j]) + A1 * b2f(v1[j]) +
                  A2 * b2f(v2[j]) + A3 * b2f(v3[j]);
      }
    }
    for (; i < cnt; ++i) {
      int2 r = rp[i];
      float A = alpha_of(r.y, h, a0, a1, a2, w0, w1, w2);
      ushort8v v = *(const ushort8v*)(xpb + (size_t)r.x * CH + c);
      #pragma unroll
      for (int j = 0; j < 8; ++j) acc[j] += A * b2f(v[j]);
    }

    const float4 b0 = *(const float4*)(bias + c);
    const float4 b1 = *(const float4*)(bias + c + 4);
    float* o = out + (size_t)n * CH + c;
    *(float4*)(o + 0) = make_float4(acc[0] + b0.x, acc[1] + b0.y, acc[2] + b0.z, acc[3] + b0.w);
    *(float4*)(o + 4) = make_float4(acc[4] + b1.x, acc[5] + b1.y, acc[6] + b1.z, acc[7] + b1.w);
  }
}

// ===========================================================================
// Cooperative mega kernel: 4 phases, grid.sync between. Grid size is chosen
// at launch from the occupancy query, so co-residency is guaranteed.
// ===========================================================================
__global__ __launch_bounds__(256, 2) void mega_kernel(
    const float* __restrict__ x,
    const int* __restrict__ e0, const int* __restrict__ e1,
    const int* __restrict__ e2,
    const float* __restrict__ a0, const float* __restrict__ a1,
    const float* __restrict__ a2,
    const float* __restrict__ nw, const float* __restrict__ W,
    const float* __restrict__ bias, float* __restrict__ out,
    unsigned short* __restrict__ xpb, long long* __restrict__ recs2,
    unsigned short* __restrict__ WTp, int* __restrict__ cursor) {
  cg::grid_group grid = cg::this_grid();
  const int tid = threadIdx.x;
  const int nblocks = gridDim.x;
  const int gtid = blockIdx.x * 256 + tid;
  const int nthreads = nblocks * 256;

  phase_prep(gtid, nthreads, W, WTp, cursor);
  __threadfence();
  grid.sync();

  phase_gemm(blockIdx.x, nblocks, tid, x, WTp, xpb);
  __threadfence();
  grid.sync();

  phase_fill(gtid, nthreads, e0, e1, e2, cursor, recs2);
  __threadfence();
  grid.sync();

  phase_gather(blockIdx.x * 4 + (tid >> 6), nblocks * 4, tid & 63,
               recs2, cursor, a0, a1, a2, nw, xpb, bias, out);
}

// ===========================================================================
// Fallback path: the proven round-9 four-kernel pipeline (290 us).
// ===========================================================================
__global__ __launch_bounds__(256) void prep_kernel(
    const float* __restrict__ W, unsigned short* __restrict__ WTp,
    int* __restrict__ cursor) {
  phase_prep(blockIdx.x * 256 + threadIdx.x, 196 * 256, W, WTp, cursor);
}

__global__ __launch_bounds__(256) void gemm_kernel(
    const float* __restrict__ x, const unsigned short* __restrict__ WTp,
    unsigned short* __restrict__ xpb) {
  phase_gemm(blockIdx.x, GEMM_TILES, threadIdx.x, x, WTp, xpb);
}

__global__ __launch_bounds__(256) void fill_kernel(
    const int* __restrict__ e0, const int* __restrict__ e1,
    const int* __restrict__ e2, int* __restrict__ cursor,
    long long* __restrict__ recs2) {
  phase_fill(blockIdx.x * 256 + threadIdx.x, 4688 * 256, e0, e1, e2, cursor, recs2);
}

__global__ __launch_bounds__(256) void gather_kernel(
    const long long* __restrict__ recs2, const int* __restrict__ cursor,
    const float* __restrict__ a0, const float* __restrict__ a1,
    const float* __restrict__ a2, const float* __restrict__ nw,
    const unsigned short* __restrict__ xpb, const float* __restrict__ bias,
    float* __restrict__ out) {
  phase_gather((blockIdx.x * 256 + threadIdx.x) >> 6, (N_NODES / 8) * 4,
               threadIdx.x & 63, recs2, cursor, a0, a1, a2, nw, xpb, bias, out);
}

// ===========================================================================
extern "C" void kernel_launch(void* const* d_in, const int* in_sizes, int n_in,
                              void* d_out, int out_size, void* d_ws, size_t ws_size,
                              hipStream_t stream) {
  const float* x    = (const float*)d_in[0];
  const int*   e0   = (const int*)d_in[1];
  const int*   e1   = (const int*)d_in[2];
  const int*   e2   = (const int*)d_in[3];
  const float* a0   = (const float*)d_in[4];
  const float* a1   = (const float*)d_in[5];
  const float* a2   = (const float*)d_in[6];
  const float* nw   = (const float*)d_in[7];
  const float* W    = (const float*)d_in[8];
  const float* bias = (const float*)d_in[9];
  float* out = (float*)d_out;

  // ---- workspace carve (~51.6 MB) ----
  char* ws = (char*)d_ws;
  size_t o = 0;
  unsigned short* xpb = (unsigned short*)(ws + o); o += (size_t)N_NODES * CH * 2;       // 25.6 MB
  long long* recs2 = (long long*)(ws + o);         o += (size_t)N_NODES * BUCKET * 8;   // 25.6 MB
  unsigned short* WTp = (unsigned short*)(ws + o); o += 65536 * 2;                      // 128 KB
  int* cursor    = (int*)(ws + o);                 o += (size_t)N_NODES * 4;            // 200 KB

  // Size the cooperative grid from the occupancy query (deterministic,
  // capture-safe; avoids hipErrorCooperativeLaunchTooLarge).
  int maxPerCU = 0;
  hipError_t qerr = hipOccupancyMaxActiveBlocksPerMultiprocessor(
      &maxPerCU, (const void*)mega_kernel, 256, 0);
  int nb = 0;
  if (qerr == hipSuccess && maxPerCU > 0) nb = (maxPerCU > 8 ? 8 : maxPerCU) * 256;

  hipError_t lerr = hipErrorUnknown;
  if (nb >= 256) {
    void* args[] = {
      (void*)&x, (void*)&e0, (void*)&e1, (void*)&e2,
      (void*)&a0, (void*)&a1, (void*)&a2,
      (void*)&nw, (void*)&W, (void*)&bias, (void*)&out,
      (void*)&xpb, (void*)&recs2, (void*)&WTp, (void*)&cursor
    };
    lerr = hipLaunchCooperativeKernel((const void*)mega_kernel, dim3(nb),
                                      dim3(256), args, 0, stream);
  }

  if (lerr != hipSuccess) {
    (void)hipGetLastError();  // clear sticky error, use the proven 4-kernel path
    prep_kernel<<<196, 256, 0, stream>>>(W, WTp, cursor);
    gemm_kernel<<<GEMM_TILES, 256, 0, stream>>>(x, WTp, xpb);
    fill_kernel<<<4688, 256, 0, stream>>>(e0, e1, e2, cursor, recs2);
    gather_kernel<<<N_NODES / 8, 256, 0, stream>>>(
        recs2, cursor, a0, a1, a2, nw, xpb, bias, out);
  }
}

// Round 12
// 248.422 us; speedup vs baseline: 2.1804x; 2.1804x over previous
//
#include <hip/hip_runtime.h>

// N = 50000 nodes, E = 400000 edges/network, M = 3 networks,
// H = 4 heads, D = 64 -> CH = 256 channels, fp32 in/out.
#define N_NODES 50000
#define N_EDGES 400000
#define TOT_E   (3 * N_EDGES)
#define CH      256
#define NHEADS  4
#define BUCKET  64   // per-node bucket stride; realized max in-degree <= 64 (verified by passes)

typedef __attribute__((ext_vector_type(8))) short short8v;
typedef __attribute__((ext_vector_type(8))) unsigned short ushort8v;
typedef __attribute__((ext_vector_type(4))) float float4v;

__device__ inline unsigned short f2b(float f) {  // fp32 -> bf16 RTNE
  union { float f; unsigned u; } x; x.f = f;
  return (unsigned short)((x.u + 0x7FFFu + ((x.u >> 16) & 1u)) >> 16);
}
__device__ inline float b2f(unsigned short s) {
  union { unsigned u; float f; } x; x.u = ((unsigned)s) << 16;
  return x.f;
}
__device__ inline float h2f(unsigned short s) {
  return (float)__builtin_bit_cast(_Float16, s);
}

// ===========================================================================
// prep: cursor[i]=0  +  W -> MFMA-fragment-ordered bf16 permutation WTp.
// ===========================================================================
__global__ __launch_bounds__(256) void prep_kernel(
    const float* __restrict__ W, unsigned short* __restrict__ WTp,
    int* __restrict__ cursor) {
  int i = blockIdx.x * 256 + threadIdx.x;
  if (i < N_NODES) cursor[i] = 0;
  if (i < 8192) {
    int f = i >> 9, ks = (i >> 6) & 7, l = i & 63;
    int lr = l & 15, lk = l >> 4;
    unsigned short* dst = WTp + (size_t)i * 8;
    #pragma unroll
    for (int j = 0; j < 8; ++j)
      dst[j] = f2b(W[(ks * 32 + lk * 8 + j) * 256 + f * 16 + lr]);
  }
}

// ===========================================================================
// GEMM: xpb = bf16(x @ W). LDS-free MFMA (16x16x32 bf16), round-9 proven.
// ===========================================================================
__global__ __launch_bounds__(256) void gemm_kernel(
    const float* __restrict__ x, const unsigned short* __restrict__ WTp,
    unsigned short* __restrict__ xpb) {
  const int tid = threadIdx.x;
  const int w = tid >> 6;
  const int l = tid & 63;
  const int lr = l & 15, lk = l >> 4;
  const int xrow = blockIdx.x * 64 + w * 16 + lr;
  const bool valid = (xrow < N_NODES);
  const short8v* __restrict__ wp = (const short8v*)WTp;

  float4v acc[16];
  #pragma unroll
  for (int f = 0; f < 16; ++f) acc[f] = (float4v)0.0f;

  for (int ks = 0; ks < 8; ++ks) {
    short8v b;
    if (valid) {
      const float4* px = (const float4*)(x + (size_t)xrow * 256 + ks * 32 + lk * 8);
      float4 u0 = px[0], u1 = px[1];
      b[0]=(short)f2b(u0.x); b[1]=(short)f2b(u0.y); b[2]=(short)f2b(u0.z); b[3]=(short)f2b(u0.w);
      b[4]=(short)f2b(u1.x); b[5]=(short)f2b(u1.y); b[6]=(short)f2b(u1.z); b[7]=(short)f2b(u1.w);
    } else {
      b = (short8v)0;
    }
    #pragma unroll
    for (int f = 0; f < 16; ++f) {
      short8v a = wp[(f * 8 + ks) * 64 + l];
      acc[f] = __builtin_amdgcn_mfma_f32_16x16x32_bf16(a, b, acc[f], 0, 0, 0);
    }
  }

  if (valid) {
    unsigned short* rowp = xpb + (size_t)xrow * 256 + lk * 4;
    #pragma unroll
    for (int f = 0; f < 16; ++f) {
      ushort4 pk;
      pk.x = f2b(acc[f][0]);
      pk.y = f2b(acc[f][1]);
      pk.z = f2b(acc[f][2]);
      pk.w = f2b(acc[f][3]);
      *(ushort4*)(rowp + f * 16) = pk;
    }
  }
}

// ===========================================================================
// VARIANT A (alpha-in-bucket; needs ~64.3 MB ws)
// fill_a: srcs[slot]=src, abuf[slot]=4xfp16 prescaled alpha.
// ===========================================================================
__global__ __launch_bounds__(256) void fill_a_kernel(
    const int* __restrict__ e0, const int* __restrict__ e1,
    const int* __restrict__ e2,
    const float* __restrict__ a0, const float* __restrict__ a1,
    const float* __restrict__ a2, const float* __restrict__ nw,
    int* __restrict__ cursor, int* __restrict__ srcs,
    ushort4* __restrict__ abuf) {
  int g = blockIdx.x * 256 + threadIdx.x;
  if (g >= TOT_E) return;
  int net = (g >= 2 * N_EDGES) ? 2 : (g >= N_EDGES ? 1 : 0);
  int e = g - net * N_EDGES;
  const int* ei = (net == 0) ? e0 : (net == 1 ? e1 : e2);
  const float* at = (net == 0) ? a0 : (net == 1 ? a1 : a2);
  const float wv = nw[net];
  int src = ei[e];
  int dst = ei[N_EDGES + e];
  float4 al = *(const float4*)(at + (size_t)e * NHEADS);
  ushort4 pk;
  pk.x = __builtin_bit_cast(unsigned short, (_Float16)(wv * al.x));
  pk.y = __builtin_bit_cast(unsigned short, (_Float16)(wv * al.y));
  pk.z = __builtin_bit_cast(unsigned short, (_Float16)(wv * al.z));
  pk.w = __builtin_bit_cast(unsigned short, (_Float16)(wv * al.w));
  int pos = atomicAdd(&cursor[dst], 1);
  if (pos < BUCKET) {
    size_t slot = (size_t)dst * BUCKET + pos;
    srcs[slot] = src;
    abuf[slot] = pk;
  }
}

// gather_a: bucket-sequential srcs+alpha, only xpb row is a random access.
__global__ __launch_bounds__(256) void gather_a_kernel(
    const int* __restrict__ srcs, const ushort4* __restrict__ abuf,
    const int* __restrict__ cursor,
    const unsigned short* __restrict__ xpb, const float* __restrict__ bias,
    float* __restrict__ out) {
  const int wid = (blockIdx.x * 256 + threadIdx.x) >> 6;
  const int lane = threadIdx.x & 63;
  const int half = lane >> 5;
  const int l = lane & 31;
  const int n = wid * 2 + half;
  const int c = l * 8;                  // channel base (8 bf16 per lane)
  const int h = l >> 3;                 // head (8 lanes per head)

  const int cnt = min(cursor[n], BUCKET);
  const int* __restrict__ sp = srcs + (size_t)n * BUCKET;
  const ushort4* __restrict__ ap = abuf + (size_t)n * BUCKET;

  float acc[8] = {};
  int i = 0;
  for (; i + 4 <= cnt; i += 4) {
    int4 s4 = *(const int4*)(sp + i);                 // 16B sequential
    ushort8v a01 = *(const ushort8v*)(ap + i);        // slots i, i+1
    ushort8v a23 = *(const ushort8v*)(ap + i + 2);    // slots i+2, i+3
    float A0 = h2f((unsigned short)a01[h]);
    float A1 = h2f((unsigned short)a01[4 + h]);
    float A2 = h2f((unsigned short)a23[h]);
    float A3 = h2f((unsigned short)a23[4 + h]);
    ushort8v v0 = *(const ushort8v*)(xpb + (size_t)s4.x * CH + c);
    ushort8v v1 = *(const ushort8v*)(xpb + (size_t)s4.y * CH + c);
    ushort8v v2 = *(const ushort8v*)(xpb + (size_t)s4.z * CH + c);
    ushort8v v3 = *(const ushort8v*)(xpb + (size_t)s4.w * CH + c);
    #pragma unroll
    for (int j = 0; j < 8; ++j) {
      acc[j] += A0 * b2f(v0[j]) + A1 * b2f(v1[j]) +
                A2 * b2f(v2[j]) + A3 * b2f(v3[j]);
    }
  }
  for (; i < cnt; ++i) {
    int s = sp[i];
    ushort4 av = ap[i];
    float A = h2f((h & 2) ? ((h & 1) ? av.w : av.z) : ((h & 1) ? av.y : av.x));
    ushort8v v = *(const ushort8v*)(xpb + (size_t)s * CH + c);
    #pragma unroll
    for (int j = 0; j < 8; ++j) acc[j] += A * b2f(v[j]);
  }

  const float4 b0 = *(const float4*)(bias + c);
  const float4 b1 = *(const float4*)(bias + c + 4);
  float* o = out + (size_t)n * CH + c;
  *(float4*)(o + 0) = make_float4(acc[0] + b0.x, acc[1] + b0.y, acc[2] + b0.z, acc[3] + b0.w);
  *(float4*)(o + 4) = make_float4(acc[4] + b1.x, acc[5] + b1.y, acc[6] + b1.z, acc[7] + b1.w);
}

// ===========================================================================
// VARIANT B (round-9 fallback, 51.6 MB ws): rec = (src, gid), alpha from attn.
// ===========================================================================
__global__ __launch_bounds__(256) void fill_b_kernel(
    const int* __restrict__ e0, const int* __restrict__ e1,
    const int* __restrict__ e2, int* __restrict__ cursor,
    long long* __restrict__ recs2) {
  int g = blockIdx.x * 256 + threadIdx.x;
  if (g >= TOT_E) return;
  int net = (g >= 2 * N_EDGES) ? 2 : (g >= N_EDGES ? 1 : 0);
  int e = g - net * N_EDGES;
  const int* ei = (net == 0) ? e0 : (net == 1 ? e1 : e2);
  int src = ei[e];
  int dst = ei[N_EDGES + e];
  int pos = atomicAdd(&cursor[dst], 1);
  if (pos < BUCKET)
    recs2[(size_t)dst * BUCKET + pos] = ((long long)g << 32) | (unsigned)src;
}

__device__ inline float alpha_of(int gid, int h, const float* __restrict__ a0,
                                 const float* __restrict__ a1,
                                 const float* __restrict__ a2,
                                 float w0, float w1, float w2) {
  int net = (gid >= 2 * N_EDGES) ? 2 : (gid >= N_EDGES ? 1 : 0);
  int e = gid - net * N_EDGES;
  const float* at = (net == 0) ? a0 : (net == 1 ? a1 : a2);
  float w = (net == 0) ? w0 : (net == 1 ? w1 : w2);
  return w * at[(size_t)e * NHEADS + h];
}

__global__ __launch_bounds__(256) void gather_b_kernel(
    const long long* __restrict__ recs2, const int* __restrict__ cursor,
    const float* __restrict__ a0, const float* __restrict__ a1,
    const float* __restrict__ a2, const float* __restrict__ nw,
    const unsigned short* __restrict__ xpb, const float* __restrict__ bias,
    float* __restrict__ out) {
  const int wid = (blockIdx.x * 256 + threadIdx.x) >> 6;
  const int lane = threadIdx.x & 63;
  const int half = lane >> 5;
  const int l = lane & 31;
  const int n = wid * 2 + half;
  const int c = l * 8;
  const int h = l >> 3;

  const float w0 = nw[0], w1 = nw[1], w2 = nw[2];
  const int cnt = min(cursor[n], BUCKET);
  const int2* __restrict__ rp = (const int2*)(recs2 + (size_t)n * BUCKET);

  float acc[8] = {};
  int i = 0;
  for (; i + 4 <= cnt; i += 4) {
    int2 r0 = rp[i + 0], r1 = rp[i + 1], r2 = rp[i + 2], r3 = rp[i + 3];
    float A0 = alpha_of(r0.y, h, a0, a1, a2, w0, w1, w2);
    float A1 = alpha_of(r1.y, h, a0, a1, a2, w0, w1, w2);
    float A2 = alpha_of(r2.y, h, a0, a1, a2, w0, w1, w2);
    float A3 = alpha_of(r3.y, h, a0, a1, a2, w0, w1, w2);
    ushort8v v0 = *(const ushort8v*)(xpb + (size_t)r0.x * CH + c);
    ushort8v v1 = *(const ushort8v*)(xpb + (size_t)r1.x * CH + c);
    ushort8v v2 = *(const ushort8v*)(xpb + (size_t)r2.x * CH + c);
    ushort8v v3 = *(const ushort8v*)(xpb + (size_t)r3.x * CH + c);
    #pragma unroll
    for (int j = 0; j < 8; ++j) {
      acc[j] += A0 * b2f(v0[j]) + A1 * b2f(v1[j]) +
                A2 * b2f(v2[j]) + A3 * b2f(v3[j]);
    }
  }
  for (; i < cnt; ++i) {
    int2 r = rp[i];
    float A = alpha_of(r.y, h, a0, a1, a2, w0, w1, w2);
    ushort8v v = *(const ushort8v*)(xpb + (size_t)r.x * CH + c);
    #pragma unroll
    for (int j = 0; j < 8; ++j) acc[j] += A * b2f(v[j]);
  }

  const float4 b0 = *(const float4*)(bias + c);
  const float4 b1 = *(const float4*)(bias + c + 4);
  float* o = out + (size_t)n * CH + c;
  *(float4*)(o + 0) = make_float4(acc[0] + b0.x, acc[1] + b0.y, acc[2] + b0.z, acc[3] + b0.w);
  *(float4*)(o + 4) = make_float4(acc[4] + b1.x, acc[5] + b1.y, acc[6] + b1.z, acc[7] + b1.w);
}

// ===========================================================================
extern "C" void kernel_launch(void* const* d_in, const int* in_sizes, int n_in,
                              void* d_out, int out_size, void* d_ws, size_t ws_size,
                              hipStream_t stream) {
  const float* x    = (const float*)d_in[0];
  const int*   e0   = (const int*)d_in[1];
  const int*   e1   = (const int*)d_in[2];
  const int*   e2   = (const int*)d_in[3];
  const float* a0   = (const float*)d_in[4];
  const float* a1   = (const float*)d_in[5];
  const float* a2   = (const float*)d_in[6];
  const float* nw   = (const float*)d_in[7];
  const float* W    = (const float*)d_in[8];
  const float* bias = (const float*)d_in[9];
  float* out = (float*)d_out;

  const int nNodeBlk = (N_NODES + 255) / 256;     // 196
  const int nEdgeBlk = (TOT_E + 255) / 256;       // 4688

  // ---- workspace carve ----
  char* ws = (char*)d_ws;
  size_t o = 0;
  unsigned short* xpb = (unsigned short*)(ws + o); o += (size_t)N_NODES * CH * 2;  // 25.6 MB
  size_t bucketBase = o;

  // Variant A needs: srcs (12.8 MB) + abuf (25.6 MB) after xpb, + WTp + cursor.
  const size_t needA = bucketBase + (size_t)N_NODES * BUCKET * (4 + 8)
                       + 65536 * 2 + (size_t)N_NODES * 4;

  if (ws_size >= needA) {
    int* srcs      = (int*)(ws + bucketBase);
    ushort4* abuf  = (ushort4*)(ws + bucketBase + (size_t)N_NODES * BUCKET * 4);
    size_t o2 = bucketBase + (size_t)N_NODES * BUCKET * 12;
    unsigned short* WTp = (unsigned short*)(ws + o2); o2 += 65536 * 2;
    int* cursor    = (int*)(ws + o2);

    prep_kernel<<<nNodeBlk, 256, 0, stream>>>(W, WTp, cursor);
    gemm_kernel<<<(N_NODES + 63) / 64, 256, 0, stream>>>(x, WTp, xpb);
    fill_a_kernel<<<nEdgeBlk, 256, 0, stream>>>(e0, e1, e2, a0, a1, a2, nw,
                                                cursor, srcs, abuf);
    gather_a_kernel<<<N_NODES / 8, 256, 0, stream>>>(
        srcs, abuf, cursor, xpb, bias, out);
  } else {
    long long* recs2 = (long long*)(ws + bucketBase);
    size_t o2 = bucketBase + (size_t)N_NODES * BUCKET * 8;
    unsigned short* WTp = (unsigned short*)(ws + o2); o2 += 65536 * 2;
    int* cursor    = (int*)(ws + o2);

    prep_kernel<<<nNodeBlk, 256, 0, stream>>>(W, WTp, cursor);
    gemm_kernel<<<(N_NODES + 63) / 64, 256, 0, stream>>>(x, WTp, xpb);
    fill_b_kernel<<<nEdgeBlk, 256, 0, stream>>>(e0, e1, e2, cursor, recs2);
    gather_b_kernel<<<N_NODES / 8, 256, 0, stream>>>(
        recs2, cursor, a0, a1, a2, nw, xpb, bias, out);
  }
}

// Round 13
// 212.767 us; speedup vs baseline: 2.5458x; 1.1676x over previous
//
#include <hip/hip_runtime.h>

// N = 50000 nodes, E = 400000 edges/network, M = 3 networks,
// H = 4 heads, D = 64 -> CH = 256 channels, fp32 in/out.
#define N_NODES 50000
#define N_EDGES 400000
#define TOT_E   (3 * N_EDGES)
#define CH      256
#define NHEADS  4
#define BUCKET  64   // per-node bucket stride; realized max in-degree <= 64

typedef __attribute__((ext_vector_type(8))) short short8v;
typedef __attribute__((ext_vector_type(8))) unsigned short ushort8v;
typedef __attribute__((ext_vector_type(4))) float float4v;

__device__ inline unsigned short f2b(float f) {  // fp32 -> bf16 RTNE
  union { float f; unsigned u; } x; x.f = f;
  return (unsigned short)((x.u + 0x7FFFu + ((x.u >> 16) & 1u)) >> 16);
}
__device__ inline float b2f(unsigned short s) {
  union { unsigned u; float f; } x; x.u = ((unsigned)s) << 16;
  return x.f;
}
__device__ inline float h2f(unsigned short s) {
  return (float)__builtin_bit_cast(_Float16, s);
}

// ===========================================================================
// prep: cursor[i]=0  +  W -> MFMA-fragment-ordered bf16 permutation WTp.
// chunk = (f*8 + ks)*64 + l ; WTp[chunk*8+i] = bf16(W[ks*32+(l>>4)*8+i][f*16+(l&15)])
// ===========================================================================
__global__ __launch_bounds__(256) void prep_kernel(
    const float* __restrict__ W, unsigned short* __restrict__ WTp,
    int* __restrict__ cursor) {
  int i = blockIdx.x * 256 + threadIdx.x;
  if (i < N_NODES) cursor[i] = 0;
  if (i < 8192) {
    int f = i >> 9, ks = (i >> 6) & 7, l = i & 63;
    int lr = l & 15, lk = l >> 4;
    unsigned short* dst = WTp + (size_t)i * 8;
    #pragma unroll
    for (int j = 0; j < 8; ++j)
      dst[j] = f2b(W[(ks * 32 + lk * 8 + j) * 256 + f * 16 + lr]);
  }
}

// ===========================================================================
// GEMM: xpb = bf16(x @ W). LDS-free MFMA (16x16x32 bf16).
// Small-tile/high-occupancy shape: block = 64 rows x 64 cols
// (blockIdx.y = column group), wave = 16 rows x 64 cols, acc[4] (16 regs).
// Grid = 782 x 4 = 3128 blocks -> latency hidden by wave count, not ILP.
// ===========================================================================
__global__ __launch_bounds__(256) void gemm_kernel(
    const float* __restrict__ x, const unsigned short* __restrict__ WTp,
    unsigned short* __restrict__ xpb) {
  const int tid = threadIdx.x;
  const int w = tid >> 6;
  const int l = tid & 63;
  const int lr = l & 15, lk = l >> 4;
  const int xrow = blockIdx.x * 64 + w * 16 + lr;
  const int fbase = blockIdx.y * 4;          // 4 f-tiles of 16 cols each
  const bool valid = (xrow < N_NODES);
  const short8v* __restrict__ wp = (const short8v*)WTp;

  float4v acc[4];
  #pragma unroll
  for (int f = 0; f < 4; ++f) acc[f] = (float4v)0.0f;

  for (int ks = 0; ks < 8; ++ks) {
    // B-frag: 8 consecutive-k fp32 of this lane's x row -> bf16
    short8v b;
    if (valid) {
      const float4* px = (const float4*)(x + (size_t)xrow * 256 + ks * 32 + lk * 8);
      float4 u0 = px[0], u1 = px[1];
      b[0]=(short)f2b(u0.x); b[1]=(short)f2b(u0.y); b[2]=(short)f2b(u0.z); b[3]=(short)f2b(u0.w);
      b[4]=(short)f2b(u1.x); b[5]=(short)f2b(u1.y); b[6]=(short)f2b(u1.z); b[7]=(short)f2b(u1.w);
    } else {
      b = (short8v)0;
    }
    #pragma unroll
    for (int f = 0; f < 4; ++f) {
      short8v a = wp[((fbase + f) * 8 + ks) * 64 + l];   // 1KB/wave, L2-hit
      acc[f] = __builtin_amdgcn_mfma_f32_16x16x32_bf16(a, b, acc[f], 0, 0, 0);
    }
  }

  if (valid) {
    unsigned short* rowp = xpb + (size_t)xrow * 256 + lk * 4;
    #pragma unroll
    for (int f = 0; f < 4; ++f) {
      ushort4 pk;
      pk.x = f2b(acc[f][0]);
      pk.y = f2b(acc[f][1]);
      pk.z = f2b(acc[f][2]);
      pk.w = f2b(acc[f][3]);
      *(ushort4*)(rowp + (fbase + f) * 16) = pk;
    }
  }
}

// ===========================================================================
// fill: bucket edges by dst; srcs[slot]=src, abuf[slot]=4xfp16 prescaled alpha.
// ===========================================================================
__global__ __launch_bounds__(256) void fill_kernel(
    const int* __restrict__ e0, const int* __restrict__ e1,
    const int* __restrict__ e2,
    const float* __restrict__ a0, const float* __restrict__ a1,
    const float* __restrict__ a2, const float* __restrict__ nw,
    int* __restrict__ cursor, int* __restrict__ srcs,
    ushort4* __restrict__ abuf) {
  int g = blockIdx.x * 256 + threadIdx.x;
  if (g >= TOT_E) return;
  int net = (g >= 2 * N_EDGES) ? 2 : (g >= N_EDGES ? 1 : 0);
  int e = g - net * N_EDGES;
  const int* ei = (net == 0) ? e0 : (net == 1 ? e1 : e2);
  const float* at = (net == 0) ? a0 : (net == 1 ? a1 : a2);
  const float wv = nw[net];
  int src = ei[e];
  int dst = ei[N_EDGES + e];
  float4 al = *(const float4*)(at + (size_t)e * NHEADS);
  ushort4 pk;
  pk.x = __builtin_bit_cast(unsigned short, (_Float16)(wv * al.x));
  pk.y = __builtin_bit_cast(unsigned short, (_Float16)(wv * al.y));
  pk.z = __builtin_bit_cast(unsigned short, (_Float16)(wv * al.z));
  pk.w = __builtin_bit_cast(unsigned short, (_Float16)(wv * al.w));
  int pos = atomicAdd(&cursor[dst], 1);
  if (pos < BUCKET) {
    size_t slot = (size_t)dst * BUCKET + pos;
    srcs[slot] = src;
    abuf[slot] = pk;
  }
}

// ===========================================================================
// gather: bucket-sequential srcs+alpha; only the xpb row is a random access.
// 2 nodes per wave, 8 bf16 ch per lane, x4 unroll + serial tail.
// ===========================================================================
__global__ __launch_bounds__(256) void gather_kernel(
    const int* __restrict__ srcs, const ushort4* __restrict__ abuf,
    const int* __restrict__ cursor,
    const unsigned short* __restrict__ xpb, const float* __restrict__ bias,
    float* __restrict__ out) {
  const int wid = (blockIdx.x * 256 + threadIdx.x) >> 6;
  const int lane = threadIdx.x & 63;
  const int half = lane >> 5;
  const int l = lane & 31;
  const int n = wid * 2 + half;
  const int c = l * 8;                  // channel base (8 bf16 per lane)
  const int h = l >> 3;                 // head (8 lanes per head)

  const int cnt = min(cursor[n], BUCKET);
  const int* __restrict__ sp = srcs + (size_t)n * BUCKET;
  const ushort4* __restrict__ ap = abuf + (size_t)n * BUCKET;

  float acc[8] = {};
  int i = 0;
  for (; i + 4 <= cnt; i += 4) {
    int4 s4 = *(const int4*)(sp + i);                 // 16B sequential
    ushort8v a01 = *(const ushort8v*)(ap + i);        // slots i, i+1
    ushort8v a23 = *(const ushort8v*)(ap + i + 2);    // slots i+2, i+3
    float A0 = h2f((unsigned short)a01[h]);
    float A1 = h2f((unsigned short)a01[4 + h]);
    float A2 = h2f((unsigned short)a23[h]);
    float A3 = h2f((unsigned short)a23[4 + h]);
    ushort8v v0 = *(const ushort8v*)(xpb + (size_t)s4.x * CH + c);
    ushort8v v1 = *(const ushort8v*)(xpb + (size_t)s4.y * CH + c);
    ushort8v v2 = *(const ushort8v*)(xpb + (size_t)s4.z * CH + c);
    ushort8v v3 = *(const ushort8v*)(xpb + (size_t)s4.w * CH + c);
    #pragma unroll
    for (int j = 0; j < 8; ++j) {
      acc[j] += A0 * b2f(v0[j]) + A1 * b2f(v1[j]) +
                A2 * b2f(v2[j]) + A3 * b2f(v3[j]);
    }
  }
  for (; i < cnt; ++i) {
    int s = sp[i];
    ushort4 av = ap[i];
    float A = h2f((h & 2) ? ((h & 1) ? av.w : av.z) : ((h & 1) ? av.y : av.x));
    ushort8v v = *(const ushort8v*)(xpb + (size_t)s * CH + c);
    #pragma unroll
    for (int j = 0; j < 8; ++j) acc[j] += A * b2f(v[j]);
  }

  const float4 b0 = *(const float4*)(bias + c);
  const float4 b1 = *(const float4*)(bias + c + 4);
  float* o = out + (size_t)n * CH + c;
  *(float4*)(o + 0) = make_float4(acc[0] + b0.x, acc[1] + b0.y, acc[2] + b0.z, acc[3] + b0.w);
  *(float4*)(o + 4) = make_float4(acc[4] + b1.x, acc[5] + b1.y, acc[6] + b1.z, acc[7] + b1.w);
}

// ===========================================================================
extern "C" void kernel_launch(void* const* d_in, const int* in_sizes, int n_in,
                              void* d_out, int out_size, void* d_ws, size_t ws_size,
                              hipStream_t stream) {
  const float* x    = (const float*)d_in[0];
  const int*   e0   = (const int*)d_in[1];
  const int*   e1   = (const int*)d_in[2];
  const int*   e2   = (const int*)d_in[3];
  const float* a0   = (const float*)d_in[4];
  const float* a1   = (const float*)d_in[5];
  const float* a2   = (const float*)d_in[6];
  const float* nw   = (const float*)d_in[7];
  const float* W    = (const float*)d_in[8];
  const float* bias = (const float*)d_in[9];
  float* out = (float*)d_out;

  // ---- workspace carve (~64.3 MB; proven to fit in round 12) ----
  char* ws = (char*)d_ws;
  size_t o = 0;
  unsigned short* xpb = (unsigned short*)(ws + o); o += (size_t)N_NODES * CH * 2;        // 25.6 MB
  int* srcs      = (int*)(ws + o);                 o += (size_t)N_NODES * BUCKET * 4;    // 12.8 MB
  ushort4* abuf  = (ushort4*)(ws + o);             o += (size_t)N_NODES * BUCKET * 8;    // 25.6 MB
  unsigned short* WTp = (unsigned short*)(ws + o); o += 65536 * 2;                       // 128 KB
  int* cursor    = (int*)(ws + o);                 o += (size_t)N_NODES * 4;             // 200 KB

  const int nNodeBlk = (N_NODES + 255) / 256;     // 196
  const int nEdgeBlk = (TOT_E + 255) / 256;       // 4688

  prep_kernel<<<nNodeBlk, 256, 0, stream>>>(W, WTp, cursor);
  gemm_kernel<<<dim3((N_NODES + 63) / 64, 4), 256, 0, stream>>>(x, WTp, xpb);
  fill_kernel<<<nEdgeBlk, 256, 0, stream>>>(e0, e1, e2, a0, a1, a2, nw,
                                            cursor, srcs, abuf);
  gather_kernel<<<N_NODES / 8, 256, 0, stream>>>(
      srcs, abuf, cursor, xpb, bias, out);
}

// Round 14
// 199.622 us; speedup vs baseline: 2.7134x; 1.0658x over previous
//
#include <hip/hip_runtime.h>

// N = 50000 nodes, E = 400000 edges/network, M = 3 networks,
// H = 4 heads, D = 64 -> CH = 256 channels, fp32 in/out.
#define N_NODES 50000
#define N_EDGES 400000
#define TOT_E   (3 * N_EDGES)
#define CH      256
#define NHEADS  4
#define BUCKET  64   // per-node bucket stride; realized max in-degree <= 64 (proven)

typedef __attribute__((ext_vector_type(8))) short short8v;
typedef __attribute__((ext_vector_type(8))) unsigned short ushort8v;
typedef __attribute__((ext_vector_type(4))) float float4v;

__device__ inline unsigned short f2b(float f) {  // fp32 -> bf16 RTNE
  union { float f; unsigned u; } x; x.f = f;
  return (unsigned short)((x.u + 0x7FFFu + ((x.u >> 16) & 1u)) >> 16);
}
__device__ inline float b2f(unsigned short s) {
  union { unsigned u; float f; } x; x.u = ((unsigned)s) << 16;
  return x.f;
}
__device__ inline float h2f(unsigned short s) {
  return (float)__builtin_bit_cast(_Float16, s);
}
__device__ inline unsigned short f2h(float f) {
  return __builtin_bit_cast(unsigned short, (_Float16)f);
}

// ===========================================================================
// prep: cursor[i]=0  +  W -> MFMA-fragment-ordered bf16 permutation WTp.
// ===========================================================================
__global__ __launch_bounds__(256) void prep_kernel(
    const float* __restrict__ W, unsigned short* __restrict__ WTp,
    int* __restrict__ cursor) {
  int i = blockIdx.x * 256 + threadIdx.x;
  if (i < N_NODES) cursor[i] = 0;
  if (i < 8192) {
    int f = i >> 9, ks = (i >> 6) & 7, l = i & 63;
    int lr = l & 15, lk = l >> 4;
    unsigned short* dst = WTp + (size_t)i * 8;
    #pragma unroll
    for (int j = 0; j < 8; ++j)
      dst[j] = f2b(W[(ks * 32 + lk * 8 + j) * 256 + f * 16 + lr]);
  }
}

// ===========================================================================
// GEMM: xpb = bf16(x @ W). LDS-free MFMA (16x16x32 bf16).
// Block = 64 rows x 128 cols (8 f-tiles, blockIdx.y in {0,1}), acc[8].
// Grid = 782 x 2 = 1564 blocks (6/CU): occupancy AND x-reuse (x read 2x).
// ===========================================================================
__global__ __launch_bounds__(256) void gemm_kernel(
    const float* __restrict__ x, const unsigned short* __restrict__ WTp,
    unsigned short* __restrict__ xpb) {
  const int tid = threadIdx.x;
  const int w = tid >> 6;
  const int l = tid & 63;
  const int lr = l & 15, lk = l >> 4;
  const int xrow = blockIdx.x * 64 + w * 16 + lr;
  const int fbase = blockIdx.y * 8;          // 8 f-tiles of 16 cols each
  const bool valid = (xrow < N_NODES);
  const short8v* __restrict__ wp = (const short8v*)WTp;

  float4v acc[8];
  #pragma unroll
  for (int f = 0; f < 8; ++f) acc[f] = (float4v)0.0f;

  for (int ks = 0; ks < 8; ++ks) {
    short8v b;
    if (valid) {
      const float4* px = (const float4*)(x + (size_t)xrow * 256 + ks * 32 + lk * 8);
      float4 u0 = px[0], u1 = px[1];
      b[0]=(short)f2b(u0.x); b[1]=(short)f2b(u0.y); b[2]=(short)f2b(u0.z); b[3]=(short)f2b(u0.w);
      b[4]=(short)f2b(u1.x); b[5]=(short)f2b(u1.y); b[6]=(short)f2b(u1.z); b[7]=(short)f2b(u1.w);
    } else {
      b = (short8v)0;
    }
    #pragma unroll
    for (int f = 0; f < 8; ++f) {
      short8v a = wp[((fbase + f) * 8 + ks) * 64 + l];   // 1KB/wave, L2-hit
      acc[f] = __builtin_amdgcn_mfma_f32_16x16x32_bf16(a, b, acc[f], 0, 0, 0);
    }
  }

  if (valid) {
    unsigned short* rowp = xpb + (size_t)xrow * 256 + lk * 4;
    #pragma unroll
    for (int f = 0; f < 8; ++f) {
      ushort4 pk;
      pk.x = f2b(acc[f][0]);
      pk.y = f2b(acc[f][1]);
      pk.z = f2b(acc[f][2]);
      pk.w = f2b(acc[f][3]);
      *(ushort4*)(rowp + (fbase + f) * 16) = pk;
    }
  }
}

// ===========================================================================
// VARIANT A (16B unified record, needs ~77.3 MB ws):
// rec = {src, (a1<<16)|a0, (a3<<16)|a2, pad} -- ONE 16B store + atomic per edge.
// ===========================================================================
__global__ __launch_bounds__(256) void fill_a_kernel(
    const int* __restrict__ e0, const int* __restrict__ e1,
    const int* __restrict__ e2,
    const float* __restrict__ a0, const float* __restrict__ a1,
    const float* __restrict__ a2, const float* __restrict__ nw,
    int* __restrict__ cursor, int4* __restrict__ recs) {
  int g = blockIdx.x * 256 + threadIdx.x;
  if (g >= TOT_E) return;
  int net = (g >= 2 * N_EDGES) ? 2 : (g >= N_EDGES ? 1 : 0);
  int e = g - net * N_EDGES;
  const int* ei = (net == 0) ? e0 : (net == 1 ? e1 : e2);
  const float* at = (net == 0) ? a0 : (net == 1 ? a1 : a2);
  const float wv = nw[net];
  int src = ei[e];
  int dst = ei[N_EDGES + e];
  float4 al = *(const float4*)(at + (size_t)e * NHEADS);
  int4 rec;
  rec.x = src;
  rec.y = ((int)f2h(wv * al.y) << 16) | (int)f2h(wv * al.x);
  rec.z = ((int)f2h(wv * al.w) << 16) | (int)f2h(wv * al.z);
  rec.w = 0;
  int pos = atomicAdd(&cursor[dst], 1);
  if (pos < BUCKET) recs[(size_t)dst * BUCKET + pos] = rec;
}

__global__ __launch_bounds__(256) void gather_a_kernel(
    const int4* __restrict__ recs, const int* __restrict__ cursor,
    const unsigned short* __restrict__ xpb, const float* __restrict__ bias,
    float* __restrict__ out) {
  const int wid = (blockIdx.x * 256 + threadIdx.x) >> 6;
  const int lane = threadIdx.x & 63;
  const int half = lane >> 5;
  const int l = lane & 31;
  const int n = wid * 2 + half;
  const int c = l * 8;                  // channel base (8 bf16 per lane)
  const int h = l >> 3;                 // head (8 lanes per head)

  const int cnt = min(cursor[n], BUCKET);
  const int4* __restrict__ rp = recs + (size_t)n * BUCKET;

  float acc[8] = {};
  int i = 0;
  for (; i + 4 <= cnt; i += 4) {
    int4 r0 = rp[i + 0], r1 = rp[i + 1], r2 = rp[i + 2], r3 = rp[i + 3];
    unsigned w0 = (h & 2) ? (unsigned)r0.z : (unsigned)r0.y;
    unsigned w1 = (h & 2) ? (unsigned)r1.z : (unsigned)r1.y;
    unsigned w2 = (h & 2) ? (unsigned)r2.z : (unsigned)r2.y;
    unsigned w3 = (h & 2) ? (unsigned)r3.z : (unsigned)r3.y;
    float A0 = h2f((unsigned short)((h & 1) ? (w0 >> 16) : (w0 & 0xffff)));
    float A1 = h2f((unsigned short)((h & 1) ? (w1 >> 16) : (w1 & 0xffff)));
    float A2 = h2f((unsigned short)((h & 1) ? (w2 >> 16) : (w2 & 0xffff)));
    float A3 = h2f((unsigned short)((h & 1) ? (w3 >> 16) : (w3 & 0xffff)));
    ushort8v v0 = *(const ushort8v*)(xpb + (size_t)r0.x * CH + c);
    ushort8v v1 = *(const ushort8v*)(xpb + (size_t)r1.x * CH + c);
    ushort8v v2 = *(const ushort8v*)(xpb + (size_t)r2.x * CH + c);
    ushort8v v3 = *(const ushort8v*)(xpb + (size_t)r3.x * CH + c);
    #pragma unroll
    for (int j = 0; j < 8; ++j) {
      acc[j] += A0 * b2f(v0[j]) + A1 * b2f(v1[j]) +
                A2 * b2f(v2[j]) + A3 * b2f(v3[j]);
    }
  }
  for (; i < cnt; ++i) {
    int4 r = rp[i];
    unsigned wd = (h & 2) ? (unsigned)r.z : (unsigned)r.y;
    float A = h2f((unsigned short)((h & 1) ? (wd >> 16) : (wd & 0xffff)));
    ushort8v v = *(const ushort8v*)(xpb + (size_t)r.x * CH + c);
    #pragma unroll
    for (int j = 0; j < 8; ++j) acc[j] += A * b2f(v[j]);
  }

  const float4 b0 = *(const float4*)(bias + c);
  const float4 b1 = *(const float4*)(bias + c + 4);
  float* o = out + (size_t)n * CH + c;
  *(float4*)(o + 0) = make_float4(acc[0] + b0.x, acc[1] + b0.y, acc[2] + b0.z, acc[3] + b0.w);
  *(float4*)(o + 4) = make_float4(acc[4] + b1.x, acc[5] + b1.y, acc[6] + b1.z, acc[7] + b1.w);
}

// ===========================================================================
// VARIANT B (round-13 proven fallback, ~64.3 MB): srcs[] + abuf[] split arrays.
// ===========================================================================
__global__ __launch_bounds__(256) void fill_b_kernel(
    const int* __restrict__ e0, const int* __restrict__ e1,
    const int* __restrict__ e2,
    const float* __restrict__ a0, const float* __restrict__ a1,
    const float* __restrict__ a2, const float* __restrict__ nw,
    int* __restrict__ cursor, int* __restrict__ srcs,
    ushort4* __restrict__ abuf) {
  int g = blockIdx.x * 256 + threadIdx.x;
  if (g >= TOT_E) return;
  int net = (g >= 2 * N_EDGES) ? 2 : (g >= N_EDGES ? 1 : 0);
  int e = g - net * N_EDGES;
  const int* ei = (net == 0) ? e0 : (net == 1 ? e1 : e2);
  const float* at = (net == 0) ? a0 : (net == 1 ? a1 : a2);
  const float wv = nw[net];
  int src = ei[e];
  int dst = ei[N_EDGES + e];
  float4 al = *(const float4*)(at + (size_t)e * NHEADS);
  ushort4 pk;
  pk.x = f2h(wv * al.x);
  pk.y = f2h(wv * al.y);
  pk.z = f2h(wv * al.z);
  pk.w = f2h(wv * al.w);
  int pos = atomicAdd(&cursor[dst], 1);
  if (pos < BUCKET) {
    size_t slot = (size_t)dst * BUCKET + pos;
    srcs[slot] = src;
    abuf[slot] = pk;
  }
}

__global__ __launch_bounds__(256) void gather_b_kernel(
    const int* __restrict__ srcs, const ushort4* __restrict__ abuf,
    const int* __restrict__ cursor,
    const unsigned short* __restrict__ xpb, const float* __restrict__ bias,
    float* __restrict__ out) {
  const int wid = (blockIdx.x * 256 + threadIdx.x) >> 6;
  const int lane = threadIdx.x & 63;
  const int half = lane >> 5;
  const int l = lane & 31;
  const int n = wid * 2 + half;
  const int c = l * 8;
  const int h = l >> 3;

  const int cnt = min(cursor[n], BUCKET);
  const int* __restrict__ sp = srcs + (size_t)n * BUCKET;
  const ushort4* __restrict__ ap = abuf + (size_t)n * BUCKET;

  float acc[8] = {};
  int i = 0;
  for (; i + 4 <= cnt; i += 4) {
    int4 s4 = *(const int4*)(sp + i);
    ushort8v a01 = *(const ushort8v*)(ap + i);
    ushort8v a23 = *(const ushort8v*)(ap + i + 2);
    float A0 = h2f((unsigned short)a01[h]);
    float A1 = h2f((unsigned short)a01[4 + h]);
    float A2 = h2f((unsigned short)a23[h]);
    float A3 = h2f((unsigned short)a23[4 + h]);
    ushort8v v0 = *(const ushort8v*)(xpb + (size_t)s4.x * CH + c);
    ushort8v v1 = *(const ushort8v*)(xpb + (size_t)s4.y * CH + c);
    ushort8v v2 = *(const ushort8v*)(xpb + (size_t)s4.z * CH + c);
    ushort8v v3 = *(const ushort8v*)(xpb + (size_t)s4.w * CH + c);
    #pragma unroll
    for (int j = 0; j < 8; ++j) {
      acc[j] += A0 * b2f(v0[j]) + A1 * b2f(v1[j]) +
                A2 * b2f(v2[j]) + A3 * b2f(v3[j]);
    }
  }
  for (; i < cnt; ++i) {
    int s = sp[i];
    ushort4 av = ap[i];
    float A = h2f((h & 2) ? ((h & 1) ? av.w : av.z) : ((h & 1) ? av.y : av.x));
    ushort8v v = *(const ushort8v*)(xpb + (size_t)s * CH + c);
    #pragma unroll
    for (int j = 0; j < 8; ++j) acc[j] += A * b2f(v[j]);
  }

  const float4 b0 = *(const float4*)(bias + c);
  const float4 b1 = *(const float4*)(bias + c + 4);
  float* o = out + (size_t)n * CH + c;
  *(float4*)(o + 0) = make_float4(acc[0] + b0.x, acc[1] + b0.y, acc[2] + b0.z, acc[3] + b0.w);
  *(float4*)(o + 4) = make_float4(acc[4] + b1.x, acc[5] + b1.y, acc[6] + b1.z, acc[7] + b1.w);
}

// ===========================================================================
extern "C" void kernel_launch(void* const* d_in, const int* in_sizes, int n_in,
                              void* d_out, int out_size, void* d_ws, size_t ws_size,
                              hipStream_t stream) {
  const float* x    = (const float*)d_in[0];
  const int*   e0   = (const int*)d_in[1];
  const int*   e1   = (const int*)d_in[2];
  const int*   e2   = (const int*)d_in[3];
  const float* a0   = (const float*)d_in[4];
  const float* a1   = (const float*)d_in[5];
  const float* a2   = (const float*)d_in[6];
  const float* nw   = (const float*)d_in[7];
  const float* W    = (const float*)d_in[8];
  const float* bias = (const float*)d_in[9];
  float* out = (float*)d_out;

  const int nNodeBlk = (N_NODES + 255) / 256;     // 196
  const int nEdgeBlk = (TOT_E + 255) / 256;       // 4688

  char* ws = (char*)d_ws;
  size_t o = 0;
  unsigned short* xpb = (unsigned short*)(ws + o); o += (size_t)N_NODES * CH * 2;  // 25.6 MB
  size_t base = o;

  // Variant A: recs 16B x 3.2M = 51.2 MB -> total ~77.3 MB
  const size_t needA = base + (size_t)N_NODES * BUCKET * 16
                       + 65536 * 2 + (size_t)N_NODES * 4;

  if (ws_size >= needA) {
    int4* recs = (int4*)(ws + base);
    size_t o2 = base + (size_t)N_NODES * BUCKET * 16;
    unsigned short* WTp = (unsigned short*)(ws + o2); o2 += 65536 * 2;
    int* cursor = (int*)(ws + o2);

    prep_kernel<<<nNodeBlk, 256, 0, stream>>>(W, WTp, cursor);
    gemm_kernel<<<dim3((N_NODES + 63) / 64, 2), 256, 0, stream>>>(x, WTp, xpb);
    fill_a_kernel<<<nEdgeBlk, 256, 0, stream>>>(e0, e1, e2, a0, a1, a2, nw,
                                                cursor, recs);
    gather_a_kernel<<<N_NODES / 8, 256, 0, stream>>>(recs, cursor, xpb, bias, out);
  } else {
    int* srcs     = (int*)(ws + base);
    ushort4* abuf = (ushort4*)(ws + base + (size_t)N_NODES * BUCKET * 4);
    size_t o2 = base + (size_t)N_NODES * BUCKET * 12;
    unsigned short* WTp = (unsigned short*)(ws + o2); o2 += 65536 * 2;
    int* cursor = (int*)(ws + o2);

    prep_kernel<<<nNodeBlk, 256, 0, stream>>>(W, WTp, cursor);
    gemm_kernel<<<dim3((N_NODES + 63) / 64, 2), 256, 0, stream>>>(x, WTp, xpb);
    fill_b_kernel<<<nEdgeBlk, 256, 0, stream>>>(e0, e1, e2, a0, a1, a2, nw,
                                                cursor, srcs, abuf);
    gather_b_kernel<<<N_NODES / 8, 256, 0, stream>>>(srcs, abuf, cursor, xpb,
                                                     bias, out);
  }
}